// Round 7
// baseline (641.050 us; speedup 1.0000x reference)
//
#include <hip/hip_runtime.h>

#define N_PTS 32768
#define DIM   512
#define KCODES 4096
#define HW    1024
#define MARGIN 0.125f
#define MAXFLAG 2048

typedef _Float16 half8 __attribute__((ext_vector_type(8)));
typedef float f32x4 __attribute__((ext_vector_type(4)));
typedef unsigned long long u64;

// ---- d_out scratch layout (bytes). gather overwrites everything at the end.
#define E16_OFF   0            // f16 [4096][512]     = 4 MB
#define BIAS_OFF  4194304      // f32 [4096]          = 16 KB
#define TOP2_OFF  4210688      // u64 [32768][4][2]   = 2 MB   (ends 6307840)
#define ZC_OFF    6307840      // f32 [2048][512]     = 4 MB   (ends 10502144)
#define Z16_OFF   10502144     // f16 [32768][512]    = 32 MB  (ends 44056576 < 64 MB)

// ---- ws layout: zeroed region first (memset only [0,16392))
// [0,16384)         rescore best u64[2048]
// [16384,16388)     count i32
// [16388,16392)     sumsq f32
// [16392,24584)     flag list i32[2048]
// [24584,155656)    k_final i32[32768]

__device__ __forceinline__ unsigned mono(float f) {
    unsigned u = __float_as_uint(f);
    return (u & 0x80000000u) ? ~u : (u | 0x80000000u);
}
__device__ __forceinline__ float unmono(unsigned m) {
    unsigned u = (m & 0x80000000u) ? (m & 0x7FFFFFFFu) : ~m;
    return __uint_as_float(u);
}

#define ASYNC16(src, dst) __builtin_amdgcn_global_load_lds( \
    (const __attribute__((address_space(1))) void*)(src), \
    (__attribute__((address_space(3))) void*)(dst), 16, 0, 0)

// ---------------------------------------------------------------- prep E (f16 convert + bias)
__global__ void prep_e_kernel(const float* __restrict__ E, _Float16* __restrict__ E16,
                              float* __restrict__ bias) {
    int k = blockIdx.x;
    int l = threadIdx.x; // 64
    const float4* row = (const float4*)(E + (size_t)k * DIM);
    float4 a = row[l * 2];
    float4 b = row[l * 2 + 1];
    half8 h;
    h[0] = (_Float16)a.x; h[1] = (_Float16)a.y; h[2] = (_Float16)a.z; h[3] = (_Float16)a.w;
    h[4] = (_Float16)b.x; h[5] = (_Float16)b.y; h[6] = (_Float16)b.z; h[7] = (_Float16)b.w;
    *(half8*)(E16 + (size_t)k * DIM + l * 8) = h;
    float s = a.x * a.x + a.y * a.y + a.z * a.z + a.w * a.w +
              b.x * b.x + b.y * b.y + b.z * b.z + b.w * b.w;
#pragma unroll
    for (int off = 32; off > 0; off >>= 1) s += __shfl_down(s, off, 64);
    if (l == 0) bias[k] = 0.5f * s;
}

// ---------------------------------------------------------------- prep Z: NCHW f32 -> [pt][dim] f16
// Block: 64 pts x 512 dims. Coalesced reads along hw; LDS transpose; coalesced
// half8 writes (g = k*256+t -> lane-contiguous 1 KB per instruction).
__global__ __launch_bounds__(256) void prep_z_kernel(const float* __restrict__ in,
                                                     _Float16* __restrict__ z16) {
    __shared__ _Float16 tile[64 * 520];   // 520-half row pitch (1040 B, 16B-aligned)
    const int t  = threadIdx.x;
    const int hw0 = blockIdx.x * 64;      // 0..15 chunks
    const int b   = blockIdx.y;           // 0..31
    const float* src = in + (size_t)b * (DIM * HW) + hw0;
    const int hl = t & 63, dq = t >> 6;
    for (int i = 0; i < 128; i++) {
        int d = i * 4 + dq;
        tile[hl * 520 + d] = (_Float16)src[((size_t)d << 10) + hl];
    }
    __syncthreads();
    const size_t zbase = (size_t)(b * 1024 + hw0) * DIM;  // in halfs
    const int w = t >> 6, L = t & 63;
#pragma unroll
    for (int k = 0; k < 16; k++) {
        int g = k * 256 + t;  // 16B chunk index within the 64x512 tile
        half8 v = *(const half8*)((const char*)tile + (size_t)(k * 4 + w) * 1040 + L * 16);
        *(half8*)(z16 + zbase + (size_t)g * 8) = v;
    }
}

// ---------------------------------------------------------------- GEMM scorer
// True tiled GEMM: block = 256 pts x (4 panels x 256 codes), 8 waves 2(M)x4(N),
// wave tile 128 pts x 64 codes, acc f32x4[8][4]. Both operands stream through
// LDS in frag-major 1-KB chunks (per-lane global src + lane-linear LDS = zero
// bank conflicts). Per wave per K-step(32 dims): 12 ds_read_b128 -> 32 MFMA
// (2.7x less LDS traffic than the previous all-waves-read-all-codes layout).
// Sync skeleton identical to the proven R5 protocol: 3 bufs, depth-2 prefetch,
// per step {vmcnt(4); barrier; stage s+2; reads; MFMA; lgkmcnt(0)}.
// Scores bit-identical to the proven kernel: same f16 RTN inputs, acc init
// -bias (exact fp32), 16 ascending 32-dim MFMA chunks, same operand order,
// same mono-pack/top-2/merge semantics.
__global__ __launch_bounds__(512, 2) void score_gemm_kernel(
    const _Float16* __restrict__ z16, const _Float16* __restrict__ E16,
    const float* __restrict__ bias, u64* __restrict__ top2p)
{
    __shared__ alignas(16) _Float16 Ab[3][8192];  // 3 x 16 KB: z chunks [P 0..15]
    __shared__ alignas(16) _Float16 Eb[3][8192];  // 3 x 16 KB: E chunks [C 0..15]
    __shared__ u64 mrg[4][256][2];                // 16 KB: per-wc running top2

    const int t    = threadIdx.x;
    const int lane = t & 63;
    const int w    = t >> 6;       // 0..7
    const int lm   = lane & 15;
    const int lq   = lane >> 4;    // 0..3
    const int wr   = w >> 2;       // 0..1 (pt half)
    const int wc   = w & 3;        // 0..3 (code quarter)
    const int Nb   = blockIdx.x;   // 0..3
    const int pt0  = blockIdx.y * 256;

    {   // zero running-top2 scratch
        u64* m = &mrg[0][0][0];
        for (int i = t; i < 2048; i += 512) m[i] = 0;
    }
    __syncthreads();

    const u64 PKNEG = ((u64)0x007FFFFFu) << 32;  // pack(-inf)

    for (int np = 0; np < 4; np++) {
        const int code0 = Nb * 1024 + np * 256;

        // per-lane bias (compiler inserts its own vmcnt before first use)
        float4 bv[4];
#pragma unroll
        for (int ci = 0; ci < 4; ci++)
            bv[ci] = *(const float4*)&bias[code0 + wc * 64 + ci * 16 + lq * 4];

        // stage K-step s (32 dims) into buf s%3: wave w loads chunks 2w,2w+1 of A and E
        auto stage_step = [&](int s) {
            const int bb = s % 3;
            const int d0 = s * 32;
#pragma unroll
            for (int j = 0; j < 2; j++) {
                const int P = 2 * w + j;
                ASYNC16(z16 + (size_t)(pt0 + P * 16 + lm) * DIM + d0 + lq * 8,
                        &Ab[bb][P * 512]);
            }
#pragma unroll
            for (int j = 0; j < 2; j++) {
                const int C = 2 * w + j;
                ASYNC16(E16 + (size_t)(code0 + C * 16 + lm) * DIM + d0 + lq * 8,
                        &Eb[bb][C * 512]);
            }
        };
        stage_step(0);
        stage_step(1);

        // acc init with exact fp32 -bias
        f32x4 acc[8][4];
#pragma unroll
        for (int ci = 0; ci < 4; ci++) {
            f32x4 bi; bi[0] = -bv[ci].x; bi[1] = -bv[ci].y; bi[2] = -bv[ci].z; bi[3] = -bv[ci].w;
#pragma unroll
            for (int pi = 0; pi < 8; pi++) acc[pi][ci] = bi;
        }

        for (int ks = 0; ks < 16; ks++) {
            // counted wait: outstanding {stage ks, stage ks+1}=8 -> retire ks's 4
            if (ks < 15) { asm volatile("s_waitcnt vmcnt(4)" ::: "memory"); }
            else         { asm volatile("s_waitcnt vmcnt(0)" ::: "memory"); }
            __builtin_amdgcn_s_barrier();
            asm volatile("" ::: "memory");
            if (ks < 14) stage_step(ks + 2);
            const int bb = ks % 3;
            half8 bfrag[8], afrag[4];
#pragma unroll
            for (int pi = 0; pi < 8; pi++)
                bfrag[pi] = *(const half8*)&Ab[bb][(wr * 8 + pi) * 512 + lane * 8];
#pragma unroll
            for (int ci = 0; ci < 4; ci++)
                afrag[ci] = *(const half8*)&Eb[bb][(wc * 4 + ci) * 512 + lane * 8];
#pragma unroll
            for (int pi = 0; pi < 8; pi++)
#pragma unroll
                for (int ci = 0; ci < 4; ci++)
                    acc[pi][ci] = __builtin_amdgcn_mfma_f32_16x16x32_f16(
                        afrag[ci], bfrag[pi], acc[pi][ci], 0, 0, 0);
            asm volatile("s_waitcnt lgkmcnt(0)" ::: "memory");
        }
        // all waves' reads retired before next panel restages buf 0
        __builtin_amdgcn_s_barrier();
        asm volatile("" ::: "memory");

        // ---- top-2 insert for this panel (threshold fast path, codes ascending)
        u64 pb1[8], pb2[8];
#pragma unroll
        for (int pi = 0; pi < 8; pi++) { pb1[pi] = PKNEG; pb2[pi] = PKNEG; }
#pragma unroll
        for (int pi = 0; pi < 8; pi++) {
            float thr = -INFINITY;
#pragma unroll
            for (int ci = 0; ci < 4; ci++) {
                f32x4 a = acc[pi][ci];
                bool hit = (a[0] > thr) | (a[1] > thr) | (a[2] > thr) | (a[3] > thr);
                if (__any(hit)) {
#pragma unroll
                    for (int r = 0; r < 4; r++) {
                        float v = a[r];
                        if (v > thr) {
                            int code = code0 + wc * 64 + ci * 16 + lq * 4 + r;
                            u64 pk = ((u64)mono(v) << 32) | (unsigned)(0xFFFu ^ (unsigned)code);
                            if (pk > pb1[pi]) { pb2[pi] = pb1[pi]; pb1[pi] = pk; }
                            else if (pk > pb2[pi]) { pb2[pi] = pk; }
                            thr = unmono((unsigned)(pb2[pi] >> 32));
                        }
                    }
                }
            }
        }
        // merge across lq groups (lanes lm, lm+16, lm+32, lm+48 share a point)
#pragma unroll
        for (int pi = 0; pi < 8; pi++) {
#pragma unroll
            for (int m = 16; m <= 32; m <<= 1) {
                u64 o1 = __shfl_xor(pb1[pi], m, 64);
                u64 o2 = __shfl_xor(pb2[pi], m, 64);
                u64 m1 = pb1[pi] > o1 ? pb1[pi] : o1;
                u64 lo = pb1[pi] > o1 ? o1 : pb1[pi];
                u64 mm = pb2[pi] > o2 ? pb2[pi] : o2;
                pb2[pi] = lo > mm ? lo : mm;
                pb1[pi] = m1;
            }
        }
        // fold into per-wc running top2 (each (wc,ptl) owned by one wave)
        if (lq == 0) {
#pragma unroll
            for (int pi = 0; pi < 8; pi++) {
                const int ptl = wr * 128 + pi * 16 + lm;
                u64 c1 = mrg[wc][ptl][0], c2 = mrg[wc][ptl][1];
                u64 m1 = c1 > pb1[pi] ? c1 : pb1[pi];
                u64 lo = c1 > pb1[pi] ? pb1[pi] : c1;
                u64 mm = c2 > pb2[pi] ? c2 : pb2[pi];
                mrg[wc][ptl][0] = m1;
                mrg[wc][ptl][1] = lo > mm ? lo : mm;
            }
        }
    }

    __syncthreads();
    // reduce 4 wc-slices -> one top2 pair per point; write this block's Nb slice
    if (t < 256) {
        u64 B1 = 0, B2 = 0;
#pragma unroll
        for (int s = 0; s < 4; s++) {
            u64 p1 = mrg[s][t][0], p2 = mrg[s][t][1];
            u64 m1 = B1 > p1 ? B1 : p1;
            u64 lo = B1 > p1 ? p1 : B1;
            u64 mm = B2 > p2 ? B2 : p2;
            B2 = lo > mm ? lo : mm;
            B1 = m1;
        }
        u64* dst = top2p + (size_t)(pt0 + t) * 8 + Nb * 2;
        dst[0] = B1; dst[1] = B2;
    }
}

// ---------------------------------------------------------------- merge 4 N-slices + flag + compact z row
__global__ void merge_compact_kernel(const u64* __restrict__ top2, const float* __restrict__ in,
                                     int* __restrict__ k_final, int* __restrict__ list,
                                     int* __restrict__ count, float* __restrict__ zc) {
    int pt = blockIdx.x * 256 + threadIdx.x;
    const u64* p = top2 + (size_t)pt * 8;
    u64 B1 = 0, B2 = 0;
#pragma unroll
    for (int s = 0; s < 4; s++) {
        u64 p1 = p[s * 2], p2 = p[s * 2 + 1];
        u64 m1 = B1 > p1 ? B1 : p1;
        u64 lo = B1 > p1 ? p1 : B1;
        u64 mm = B2 > p2 ? B2 : p2;
        B2 = lo > mm ? lo : mm;
        B1 = m1;
    }
    k_final[pt] = 0xFFF ^ (int)(B1 & 0xFFFull);
    float s1 = unmono((unsigned)(B1 >> 32));
    float s2 = unmono((unsigned)(B2 >> 32));
    if (s1 - s2 < MARGIN) {
        int idx = atomicAdd(count, 1);
        if (idx < MAXFLAG) {
            list[idx] = pt;
            const float* zb = in + (size_t)(pt >> 10) * (DIM * HW) + (pt & 1023);
            float* dst = zc + (size_t)idx * DIM;
#pragma unroll 8
            for (int d = 0; d < DIM; d++) dst[d] = zb[(size_t)d << 10];
        }
    }
}

// ---------------------------------------------------------------- exact fp32 rescore (coalesced zc reads)
__global__ __launch_bounds__(256) void rescore_kernel(
    const float* __restrict__ zc, const float* __restrict__ E,
    const float* __restrict__ bias, const int* __restrict__ count,
    u64* __restrict__ rb)
{
    __shared__ float As[16][128];
    __shared__ float Bs[16][132];

    int cnt = *count; if (cnt > MAXFLAG) cnt = MAXFLAG;
    const int t  = threadIdx.x;
    const int k0 = blockIdx.x * 128;
    const int r0 = blockIdx.y * 128;
    if (r0 >= cnt) return;

    float acc[8][8];
#pragma unroll
    for (int i = 0; i < 8; i++)
#pragma unroll
        for (int j = 0; j < 8; j++) acc[i][j] = 0.f;

    const int ra = (t >> 4) << 2;
    const int cb = (t & 15) << 2;

    for (int d0 = 0; d0 < DIM; d0 += 16) {
        {
            int j   = t >> 2;
            int dd4 = (t & 3) << 2;
            int rA = r0 + j;        if (rA >= cnt) rA = cnt - 1;
            int rB = r0 + j + 64;   if (rB >= cnt) rB = cnt - 1;
            float4 v0 = *(const float4*)&zc[(size_t)rA * DIM + d0 + dd4];
            float4 v1 = *(const float4*)&zc[(size_t)rB * DIM + d0 + dd4];
            As[dd4 + 0][j] = v0.x; As[dd4 + 1][j] = v0.y;
            As[dd4 + 2][j] = v0.z; As[dd4 + 3][j] = v0.w;
            As[dd4 + 0][j + 64] = v1.x; As[dd4 + 1][j + 64] = v1.y;
            As[dd4 + 2][j + 64] = v1.z; As[dd4 + 3][j + 64] = v1.w;
        }
        {
            int j   = t >> 2;
            int dd4 = (t & 3) << 2;
            const float* p = E + (size_t)(k0 + j) * DIM + d0 + dd4;
            float4 v0 = *(const float4*)p;
            float4 v1 = *(const float4*)(p + (size_t)64 * DIM);
            Bs[dd4 + 0][j] = v0.x; Bs[dd4 + 1][j] = v0.y;
            Bs[dd4 + 2][j] = v0.z; Bs[dd4 + 3][j] = v0.w;
            Bs[dd4 + 0][j + 64] = v1.x; Bs[dd4 + 1][j + 64] = v1.y;
            Bs[dd4 + 2][j + 64] = v1.z; Bs[dd4 + 3][j + 64] = v1.w;
        }
        __syncthreads();
#pragma unroll
        for (int dd = 0; dd < 16; dd++) {
            float4 a0 = *(const float4*)&As[dd][ra];
            float4 a1 = *(const float4*)&As[dd][ra + 64];
            float4 b0 = *(const float4*)&Bs[dd][cb];
            float4 b1v = *(const float4*)&Bs[dd][cb + 64];
            float av[8] = {a0.x, a0.y, a0.z, a0.w, a1.x, a1.y, a1.z, a1.w};
            float bv[8] = {b0.x, b0.y, b0.z, b0.w, b1v.x, b1v.y, b1v.z, b1v.w};
#pragma unroll
            for (int i = 0; i < 8; i++)
#pragma unroll
                for (int j = 0; j < 8; j++)
                    acc[i][j] = fmaf(av[i], bv[j], acc[i][j]);
        }
        __syncthreads();
    }

    float bcol[8];
#pragma unroll
    for (int j = 0; j < 8; j++) {
        int k = k0 + ((j < 4) ? (cb + j) : (64 + cb + j - 4));
        bcol[j] = bias[k];
    }
    u64 pk[8];
#pragma unroll
    for (int i = 0; i < 8; i++) {
        u64 bestp = 0ull;
#pragma unroll
        for (int j = 0; j < 8; j++) {
            int k = k0 + ((j < 4) ? (cb + j) : (64 + cb + j - 4));
            float s = acc[i][j] - bcol[j];
            u64 p = ((u64)mono(s) << 32) | (u64)(~(unsigned)k);
            if (p > bestp) bestp = p;
        }
        pk[i] = bestp;
    }
#pragma unroll
    for (int i = 0; i < 8; i++) {
#pragma unroll
        for (int off = 8; off > 0; off >>= 1) {
            u64 o = __shfl_down(pk[i], off, 16);
            if (o > pk[i]) pk[i] = o;
        }
    }
    if ((t & 15) == 0) {
#pragma unroll
        for (int i = 0; i < 8; i++) {
            int row = r0 + ((i < 4) ? (ra + i) : (64 + ra + i - 4));
            int slot = row < cnt ? row : cnt - 1;
            atomicMax(&rb[slot], pk[i]);
        }
    }
}

__global__ void apply_kernel(const int* __restrict__ list, const int* __restrict__ count,
                             const u64* __restrict__ rb, int* __restrict__ k_final) {
    int i = blockIdx.x * 256 + threadIdx.x;
    int cnt = *count; if (cnt > MAXFLAG) cnt = MAXFLAG;
    if (i < cnt) k_final[list[i]] = (int)(~(unsigned)(rb[i] & 0xffffffffull));
}

// ---------------------------------------------------------------- gather + loss
__global__ void gather_kernel(const float* __restrict__ in, const float* __restrict__ E,
                              const int* __restrict__ k_final,
                              float* __restrict__ out, float* __restrict__ sumsq)
{
    const int t  = threadIdx.x;
    const int tx = t & 63;
    const int ty = t >> 6;
    const int n  = blockIdx.x * 64 + tx;
    const int k  = k_final[n];
    const float* erow = E + (size_t)k * DIM;
    const size_t base = (size_t)(n >> 10) * (DIM * HW) + (n & 1023);
    float local = 0.f;
    for (int d = ty; d < DIM; d += 4) {
        float q = erow[d];
        size_t idx = base + ((size_t)d << 10);
        float z = in[idx];
        out[idx] = q;
        float df = z - q;
        local = fmaf(df, df, local);
    }
#pragma unroll
    for (int off = 32; off > 0; off >>= 1) local += __shfl_down(local, off, 64);
    __shared__ float red[4];
    if (tx == 0) red[ty] = local;
    __syncthreads();
    if (t == 0) atomicAdd(sumsq, red[0] + red[1] + red[2] + red[3]);
}

__global__ void finalize_kernel(const float* __restrict__ sumsq, float* __restrict__ out_loss) {
    *out_loss = 1.25f * (*sumsq) * (1.0f / 16777216.0f);
}

// ----------------------------------------------------------------
extern "C" void kernel_launch(void* const* d_in, const int* in_sizes, int n_in,
                              void* d_out, int out_size, void* d_ws, size_t ws_size,
                              hipStream_t stream) {
    const float* in = (const float*)d_in[0];
    const float* E  = (const float*)d_in[1];
    float* out = (float*)d_out;
    char* ob = (char*)d_out;

    _Float16* E16 = (_Float16*)(ob + E16_OFF);
    float* bias   = (float*)(ob + BIAS_OFF);
    u64* top2p    = (u64*)(ob + TOP2_OFF);
    float* zc     = (float*)(ob + ZC_OFF);
    _Float16* z16 = (_Float16*)(ob + Z16_OFF);

    u64* rb      = (u64*)d_ws;
    int* count   = (int*)((char*)d_ws + 16384);
    float* sumsq = (float*)((char*)d_ws + 16388);
    int* list    = (int*)((char*)d_ws + 16392);
    int* k_final = (int*)((char*)d_ws + 24584);

    hipMemsetAsync(d_ws, 0, 16392, stream);

    prep_e_kernel<<<KCODES, 64, 0, stream>>>(E, E16, bias);
    prep_z_kernel<<<dim3(16, 32), 256, 0, stream>>>(in, z16);

    score_gemm_kernel<<<dim3(4, 128), 512, 0, stream>>>(z16, E16, bias, top2p);

    merge_compact_kernel<<<128, 256, 0, stream>>>(top2p, in, k_final, list, count, zc);

    rescore_kernel<<<dim3(32, 16), 256, 0, stream>>>(zc, E, bias, count, rb);
    apply_kernel<<<8, 256, 0, stream>>>(list, count, rb, k_final);

    gather_kernel<<<N_PTS / 64, 256, 0, stream>>>(in, E, k_final, out, sumsq);
    finalize_kernel<<<1, 1, 0, stream>>>(sumsq, out + 16777216);
}

// Round 8
// 607.336 us; speedup vs baseline: 1.0555x; 1.0555x over previous
//
#include <hip/hip_runtime.h>

#define N_PTS 32768
#define DIM   512
#define KCODES 4096
#define HW    1024
#define MARGIN 0.125f
#define MAXFLAG 2048

typedef _Float16 half8 __attribute__((ext_vector_type(8)));
typedef float f32x4 __attribute__((ext_vector_type(4)));
typedef unsigned long long u64;

// ---- d_out scratch layout (bytes). gather overwrites everything at the end.
#define E16_OFF   0            // f16 [4096][512]     = 4 MB
#define BIAS_OFF  4194304      // f32 [4096]          = 16 KB
#define TOP2_OFF  4210688      // u64 [32768][2ks][2] = 1 MB   (ends 5259264)
#define ZC_OFF    5259264      // f32 [2048][512]     = 4 MB   (ends 9453568)
#define Z16_OFF   10502144     // f16 [32768][512]    = 32 MB  (ends 44056576 < 64 MB)

// ---- ws layout: zeroed region first (memset only [0,16392))
// [0,16384)         rescore best u64[2048]
// [16384,16388)     count i32
// [16388,16392)     sumsq f32
// [16392,24584)     flag list i32[2048]
// [24584,155656)    k_final i32[32768]

__device__ __forceinline__ unsigned mono(float f) {
    unsigned u = __float_as_uint(f);
    return (u & 0x80000000u) ? ~u : (u | 0x80000000u);
}
__device__ __forceinline__ float unmono(unsigned m) {
    unsigned u = (m & 0x80000000u) ? (m & 0x7FFFFFFFu) : ~m;
    return __uint_as_float(u);
}

#define ASYNC16(src, dst) __builtin_amdgcn_global_load_lds( \
    (const __attribute__((address_space(1))) void*)(src), \
    (__attribute__((address_space(3))) void*)(dst), 16, 0, 0)

// ---------------------------------------------------------------- prep E (f16 convert + bias)
__global__ void prep_e_kernel(const float* __restrict__ E, _Float16* __restrict__ E16,
                              float* __restrict__ bias) {
    int k = blockIdx.x;
    int l = threadIdx.x; // 64
    const float4* row = (const float4*)(E + (size_t)k * DIM);
    float4 a = row[l * 2];
    float4 b = row[l * 2 + 1];
    half8 h;
    h[0] = (_Float16)a.x; h[1] = (_Float16)a.y; h[2] = (_Float16)a.z; h[3] = (_Float16)a.w;
    h[4] = (_Float16)b.x; h[5] = (_Float16)b.y; h[6] = (_Float16)b.z; h[7] = (_Float16)b.w;
    *(half8*)(E16 + (size_t)k * DIM + l * 8) = h;
    float s = a.x * a.x + a.y * a.y + a.z * a.z + a.w * a.w +
              b.x * b.x + b.y * b.y + b.z * b.z + b.w * b.w;
#pragma unroll
    for (int off = 32; off > 0; off >>= 1) s += __shfl_down(s, off, 64);
    if (l == 0) bias[k] = 0.5f * s;
}

// ---------------------------------------------------------------- prep Z: NCHW f32 -> [pt][dim] f16
// (validated absmax-0 in R7) Block: 64 pts x 512 dims; LDS transpose.
__global__ __launch_bounds__(256) void prep_z_kernel(const float* __restrict__ in,
                                                     _Float16* __restrict__ z16) {
    __shared__ _Float16 tile[64 * 520];   // 520-half row pitch (1040 B, 16B-aligned)
    const int t  = threadIdx.x;
    const int hw0 = blockIdx.x * 64;      // 0..15 chunks
    const int b   = blockIdx.y;           // 0..31
    const float* src = in + (size_t)b * (DIM * HW) + hw0;
    const int hl = t & 63, dq = t >> 6;
    for (int i = 0; i < 128; i++) {
        int d = i * 4 + dq;
        tile[hl * 520 + d] = (_Float16)src[((size_t)d << 10) + hl];
    }
    __syncthreads();
    const size_t zbase = (size_t)(b * 1024 + hw0) * DIM;  // in halfs
    const int w = t >> 6, L = t & 63;
#pragma unroll
    for (int k = 0; k < 16; k++) {
        int g = k * 256 + t;  // 16B chunk index within the 64x512 tile
        half8 v = *(const half8*)((const char*)tile + (size_t)(k * 4 + w) * 1040 + L * 16);
        *(half8*)(z16 + zbase + (size_t)g * 8) = v;
    }
}

// ---------------------------------------------------------------- GEMM scorer (R8)
// Validated R7 GEMM core (layouts proven absmax-0) with the regression fixed:
// grid (2 ks-halves, 128 pt-slices) = 256 blocks = 1/CU; each block scores
// 256 pts x 2048 codes as 8 panels of 256 codes. Wave (wr,wc) of 8 owns
// 128 pts x 64 codes; acc f32x4[8][4]. Flat 128-step K-loop (panel = step>>4,
// kk = step&15), 3 x 32 KB LDS buffers, depth-2 counted-vmcnt prefetch:
// per step {vmcnt(4); barrier; stage step+2; 12 ds_read frags; 32 MFMA;
// lgkmcnt(0)}. Bias in LDS (no loop VMEM besides the 4 ASYNC16/step).
// KEY FIX vs R7: pb1/pb2 top-2 state persists across ALL panels (threshold
// stays warm over 2048 codes -> __any skip path dominant), merge/fold runs
// once at the end. Scores bit-identical: same f16 inputs, -bias fp32 init,
// 16 ascending K-chunks, same MFMA operand order, same u64 packing.
__global__ __launch_bounds__(512, 2) void score_gemm_kernel(
    const _Float16* __restrict__ z16, const _Float16* __restrict__ E16,
    const float* __restrict__ bias, u64* __restrict__ top2)
{
    __shared__ alignas(16) _Float16 Ab[3][8192];  // 3 x 16 KB: z chunks [P 0..15]
    __shared__ alignas(16) _Float16 Eb[3][8192];  // 3 x 16 KB: E chunks [C 0..15]
    __shared__ alignas(16) float bias_sm[2048];   // 8 KB
    __shared__ u64 mrg[4][256][2];                // 16 KB

    const int t    = threadIdx.x;
    const int lane = t & 63;
    const int w    = t >> 6;       // 0..7
    const int lm   = lane & 15;
    const int lq   = lane >> 4;    // 0..3
    const int wr   = w >> 2;       // 0..1 (pt half)
    const int wc   = w & 3;        // 0..3 (code quarter)
    const int ks   = blockIdx.x;   // 0..1
    const int pt0  = blockIdx.y * 256;
    const int cbase = ks * 2048;

    // bias chunk for this half into LDS (1 ASYNC16 per wave, oldest VMEM op)
    ASYNC16(bias + cbase + w * 256 + lane * 4, &bias_sm[w * 256]);

    // stage one K-step (32 dims) of 256 pts + 256 codes into buffer bb
    auto stage = [&](int bb, int np, int kk) {
        const int code0 = cbase + np * 256;
        const int d0 = kk * 32;
#pragma unroll
        for (int j = 0; j < 2; j++) {
            const int P = 2 * w + j;
            ASYNC16(z16 + (size_t)(pt0 + P * 16 + lm) * DIM + d0 + lq * 8,
                    &Ab[bb][P * 512]);
        }
#pragma unroll
        for (int j = 0; j < 2; j++) {
            const int C = 2 * w + j;
            ASYNC16(E16 + (size_t)(code0 + C * 16 + lm) * DIM + d0 + lq * 8,
                    &Eb[bb][C * 512]);
        }
    };
    stage(0, 0, 0);
    stage(1, 0, 1);

    const u64 PKNEG = ((u64)0x007FFFFFu) << 32;  // pack(-inf)
    u64 pb1[8], pb2[8];
#pragma unroll
    for (int pi = 0; pi < 8; pi++) { pb1[pi] = PKNEG; pb2[pi] = PKNEG; }

    f32x4 acc[8][4];
    int bb = 0;

    for (int step = 0; step < 128; step++) {
        const int np = step >> 4, kk = step & 15;
        // counted wait: 8 outstanding -> 4 => this step's 4 loads landed
        // (step 0: 9 outstanding -> retires bias + step0's 4)
        if (step < 127) { asm volatile("s_waitcnt vmcnt(4)" ::: "memory"); }
        else            { asm volatile("s_waitcnt vmcnt(0)" ::: "memory"); }
        __builtin_amdgcn_s_barrier();
        asm volatile("" ::: "memory");
        if (step < 126) {
            const int s2 = step + 2;
            int b2 = bb + 2; if (b2 >= 3) b2 -= 3;
            stage(b2, s2 >> 4, s2 & 15);
        }
        if (kk == 0) {
            // acc init with exact fp32 -bias (from LDS)
            const int bl = np * 256 + wc * 64;
#pragma unroll
            for (int ci = 0; ci < 4; ci++) {
                const float4 bv = *(const float4*)&bias_sm[bl + ci * 16 + lq * 4];
                f32x4 bi; bi[0] = -bv.x; bi[1] = -bv.y; bi[2] = -bv.z; bi[3] = -bv.w;
#pragma unroll
                for (int pi = 0; pi < 8; pi++) acc[pi][ci] = bi;
            }
        }
        half8 bfrag[8], afrag[4];
#pragma unroll
        for (int pi = 0; pi < 8; pi++)
            bfrag[pi] = *(const half8*)&Ab[bb][(wr * 8 + pi) * 512 + lane * 8];
#pragma unroll
        for (int ci = 0; ci < 4; ci++)
            afrag[ci] = *(const half8*)&Eb[bb][(wc * 4 + ci) * 512 + lane * 8];
#pragma unroll
        for (int pi = 0; pi < 8; pi++)
#pragma unroll
            for (int ci = 0; ci < 4; ci++)
                acc[pi][ci] = __builtin_amdgcn_mfma_f32_16x16x32_f16(
                    afrag[ci], bfrag[pi], acc[pi][ci], 0, 0, 0);
        // my ds_reads of bb retired => safe for re-stage after next barrier
        asm volatile("s_waitcnt lgkmcnt(0)" ::: "memory");

        if (kk == 15) {
            // ---- top-2 insert, warm threshold persists across panels
            const int code0 = cbase + np * 256 + wc * 64;
#pragma unroll
            for (int pi = 0; pi < 8; pi++) {
                float th = unmono((unsigned)(pb2[pi] >> 32));
#pragma unroll
                for (int ci = 0; ci < 4; ci++) {
                    f32x4 a = acc[pi][ci];
                    bool hit = (a[0] > th) | (a[1] > th) | (a[2] > th) | (a[3] > th);
                    if (__any(hit)) {
#pragma unroll
                        for (int r = 0; r < 4; r++) {
                            float v = a[r];
                            if (v > th) {
                                int code = code0 + ci * 16 + lq * 4 + r;
                                u64 pk = ((u64)mono(v) << 32) | (unsigned)(0xFFFu ^ (unsigned)code);
                                if (pk > pb1[pi]) { pb2[pi] = pb1[pi]; pb1[pi] = pk; }
                                else if (pk > pb2[pi]) { pb2[pi] = pk; }
                                th = unmono((unsigned)(pb2[pi] >> 32));
                            }
                        }
                    }
                }
            }
        }
        bb = bb + 1; if (bb == 3) bb = 0;
    }

    // ---- merge across lq groups (lanes lm, lm+16, lm+32, lm+48 share a point)
#pragma unroll
    for (int pi = 0; pi < 8; pi++) {
#pragma unroll
        for (int m = 16; m <= 32; m <<= 1) {
            u64 o1 = __shfl_xor(pb1[pi], m, 64);
            u64 o2 = __shfl_xor(pb2[pi], m, 64);
            u64 m1 = pb1[pi] > o1 ? pb1[pi] : o1;
            u64 lo = pb1[pi] > o1 ? o1 : pb1[pi];
            u64 mm = pb2[pi] > o2 ? pb2[pi] : o2;
            pb2[pi] = lo > mm ? lo : mm;
            pb1[pi] = m1;
        }
    }
    // one writer per (wc, ptl): direct store
    if (lq == 0) {
#pragma unroll
        for (int pi = 0; pi < 8; pi++) {
            const int ptl = wr * 128 + pi * 16 + lm;
            mrg[wc][ptl][0] = pb1[pi];
            mrg[wc][ptl][1] = pb2[pi];
        }
    }
    __syncthreads();
    // reduce 4 wc-slices -> one top2 pair per point; write this block's ks slice
    if (t < 256) {
        u64 B1 = 0, B2 = 0;
#pragma unroll
        for (int s = 0; s < 4; s++) {
            u64 p1 = mrg[s][t][0], p2 = mrg[s][t][1];
            u64 m1 = B1 > p1 ? B1 : p1;
            u64 lo = B1 > p1 ? p1 : B1;
            u64 mm = B2 > p2 ? B2 : p2;
            B2 = lo > mm ? lo : mm;
            B1 = m1;
        }
        u64* dst = top2 + (size_t)(pt0 + t) * 4 + ks * 2;
        dst[0] = B1; dst[1] = B2;
    }
}

// ---------------------------------------------------------------- merge 2 k-splits + flag + compact z row
__global__ void merge_compact_kernel(const u64* __restrict__ top2, const float* __restrict__ in,
                                     int* __restrict__ k_final, int* __restrict__ list,
                                     int* __restrict__ count, float* __restrict__ zc) {
    int pt = blockIdx.x * 256 + threadIdx.x;
    const u64* p = top2 + (size_t)pt * 4;
    u64 B1 = 0, B2 = 0;
#pragma unroll
    for (int ks = 0; ks < 2; ks++) {
        u64 p1 = p[ks * 2], p2 = p[ks * 2 + 1];
        u64 m1 = B1 > p1 ? B1 : p1;
        u64 lo = B1 > p1 ? p1 : B1;
        u64 mm = B2 > p2 ? B2 : p2;
        B2 = lo > mm ? lo : mm;
        B1 = m1;
    }
    k_final[pt] = 0xFFF ^ (int)(B1 & 0xFFFull);
    float s1 = unmono((unsigned)(B1 >> 32));
    float s2 = unmono((unsigned)(B2 >> 32));
    if (s1 - s2 < MARGIN) {
        int idx = atomicAdd(count, 1);
        if (idx < MAXFLAG) {
            list[idx] = pt;
            const float* zb = in + (size_t)(pt >> 10) * (DIM * HW) + (pt & 1023);
            float* dst = zc + (size_t)idx * DIM;
#pragma unroll 8
            for (int d = 0; d < DIM; d++) dst[d] = zb[(size_t)d << 10];
        }
    }
}

// ---------------------------------------------------------------- exact fp32 rescore (coalesced zc reads)
__global__ __launch_bounds__(256) void rescore_kernel(
    const float* __restrict__ zc, const float* __restrict__ E,
    const float* __restrict__ bias, const int* __restrict__ count,
    u64* __restrict__ rb)
{
    __shared__ float As[16][128];
    __shared__ float Bs[16][132];

    int cnt = *count; if (cnt > MAXFLAG) cnt = MAXFLAG;
    const int t  = threadIdx.x;
    const int k0 = blockIdx.x * 128;
    const int r0 = blockIdx.y * 128;
    if (r0 >= cnt) return;

    float acc[8][8];
#pragma unroll
    for (int i = 0; i < 8; i++)
#pragma unroll
        for (int j = 0; j < 8; j++) acc[i][j] = 0.f;

    const int ra = (t >> 4) << 2;
    const int cb = (t & 15) << 2;

    for (int d0 = 0; d0 < DIM; d0 += 16) {
        {
            int j   = t >> 2;
            int dd4 = (t & 3) << 2;
            int rA = r0 + j;        if (rA >= cnt) rA = cnt - 1;
            int rB = r0 + j + 64;   if (rB >= cnt) rB = cnt - 1;
            float4 v0 = *(const float4*)&zc[(size_t)rA * DIM + d0 + dd4];
            float4 v1 = *(const float4*)&zc[(size_t)rB * DIM + d0 + dd4];
            As[dd4 + 0][j] = v0.x; As[dd4 + 1][j] = v0.y;
            As[dd4 + 2][j] = v0.z; As[dd4 + 3][j] = v0.w;
            As[dd4 + 0][j + 64] = v1.x; As[dd4 + 1][j + 64] = v1.y;
            As[dd4 + 2][j + 64] = v1.z; As[dd4 + 3][j + 64] = v1.w;
        }
        {
            int j   = t >> 2;
            int dd4 = (t & 3) << 2;
            const float* p = E + (size_t)(k0 + j) * DIM + d0 + dd4;
            float4 v0 = *(const float4*)p;
            float4 v1 = *(const float4*)(p + (size_t)64 * DIM);
            Bs[dd4 + 0][j] = v0.x; Bs[dd4 + 1][j] = v0.y;
            Bs[dd4 + 2][j] = v0.z; Bs[dd4 + 3][j] = v0.w;
            Bs[dd4 + 0][j + 64] = v1.x; Bs[dd4 + 1][j + 64] = v1.y;
            Bs[dd4 + 2][j + 64] = v1.z; Bs[dd4 + 3][j + 64] = v1.w;
        }
        __syncthreads();
#pragma unroll
        for (int dd = 0; dd < 16; dd++) {
            float4 a0 = *(const float4*)&As[dd][ra];
            float4 a1 = *(const float4*)&As[dd][ra + 64];
            float4 b0 = *(const float4*)&Bs[dd][cb];
            float4 b1v = *(const float4*)&Bs[dd][cb + 64];
            float av[8] = {a0.x, a0.y, a0.z, a0.w, a1.x, a1.y, a1.z, a1.w};
            float bv[8] = {b0.x, b0.y, b0.z, b0.w, b1v.x, b1v.y, b1v.z, b1v.w};
#pragma unroll
            for (int i = 0; i < 8; i++)
#pragma unroll
                for (int j = 0; j < 8; j++)
                    acc[i][j] = fmaf(av[i], bv[j], acc[i][j]);
        }
        __syncthreads();
    }

    float bcol[8];
#pragma unroll
    for (int j = 0; j < 8; j++) {
        int k = k0 + ((j < 4) ? (cb + j) : (64 + cb + j - 4));
        bcol[j] = bias[k];
    }
    u64 pk[8];
#pragma unroll
    for (int i = 0; i < 8; i++) {
        u64 bestp = 0ull;
#pragma unroll
        for (int j = 0; j < 8; j++) {
            int k = k0 + ((j < 4) ? (cb + j) : (64 + cb + j - 4));
            float s = acc[i][j] - bcol[j];
            u64 p = ((u64)mono(s) << 32) | (u64)(~(unsigned)k);
            if (p > bestp) bestp = p;
        }
        pk[i] = bestp;
    }
#pragma unroll
    for (int i = 0; i < 8; i++) {
#pragma unroll
        for (int off = 8; off > 0; off >>= 1) {
            u64 o = __shfl_down(pk[i], off, 16);
            if (o > pk[i]) pk[i] = o;
        }
    }
    if ((t & 15) == 0) {
#pragma unroll
        for (int i = 0; i < 8; i++) {
            int row = r0 + ((i < 4) ? (ra + i) : (64 + ra + i - 4));
            int slot = row < cnt ? row : cnt - 1;
            atomicMax(&rb[slot], pk[i]);
        }
    }
}

__global__ void apply_kernel(const int* __restrict__ list, const int* __restrict__ count,
                             const u64* __restrict__ rb, int* __restrict__ k_final) {
    int i = blockIdx.x * 256 + threadIdx.x;
    int cnt = *count; if (cnt > MAXFLAG) cnt = MAXFLAG;
    if (i < cnt) k_final[list[i]] = (int)(~(unsigned)(rb[i] & 0xffffffffull));
}

// ---------------------------------------------------------------- gather + loss
__global__ void gather_kernel(const float* __restrict__ in, const float* __restrict__ E,
                              const int* __restrict__ k_final,
                              float* __restrict__ out, float* __restrict__ sumsq)
{
    const int t  = threadIdx.x;
    const int tx = t & 63;
    const int ty = t >> 6;
    const int n  = blockIdx.x * 64 + tx;
    const int k  = k_final[n];
    const float* erow = E + (size_t)k * DIM;
    const size_t base = (size_t)(n >> 10) * (DIM * HW) + (n & 1023);
    float local = 0.f;
    for (int d = ty; d < DIM; d += 4) {
        float q = erow[d];
        size_t idx = base + ((size_t)d << 10);
        float z = in[idx];
        out[idx] = q;
        float df = z - q;
        local = fmaf(df, df, local);
    }
#pragma unroll
    for (int off = 32; off > 0; off >>= 1) local += __shfl_down(local, off, 64);
    __shared__ float red[4];
    if (tx == 0) red[ty] = local;
    __syncthreads();
    if (t == 0) atomicAdd(sumsq, red[0] + red[1] + red[2] + red[3]);
}

__global__ void finalize_kernel(const float* __restrict__ sumsq, float* __restrict__ out_loss) {
    *out_loss = 1.25f * (*sumsq) * (1.0f / 16777216.0f);
}

// ----------------------------------------------------------------
extern "C" void kernel_launch(void* const* d_in, const int* in_sizes, int n_in,
                              void* d_out, int out_size, void* d_ws, size_t ws_size,
                              hipStream_t stream) {
    const float* in = (const float*)d_in[0];
    const float* E  = (const float*)d_in[1];
    float* out = (float*)d_out;
    char* ob = (char*)d_out;

    _Float16* E16 = (_Float16*)(ob + E16_OFF);
    float* bias   = (float*)(ob + BIAS_OFF);
    u64* top2     = (u64*)(ob + TOP2_OFF);
    float* zc     = (float*)(ob + ZC_OFF);
    _Float16* z16 = (_Float16*)(ob + Z16_OFF);

    u64* rb      = (u64*)d_ws;
    int* count   = (int*)((char*)d_ws + 16384);
    float* sumsq = (float*)((char*)d_ws + 16388);
    int* list    = (int*)((char*)d_ws + 16392);
    int* k_final = (int*)((char*)d_ws + 24584);

    hipMemsetAsync(d_ws, 0, 16392, stream);

    prep_e_kernel<<<KCODES, 64, 0, stream>>>(E, E16, bias);
    prep_z_kernel<<<dim3(16, 32), 256, 0, stream>>>(in, z16);

    score_gemm_kernel<<<dim3(2, 128), 512, 0, stream>>>(z16, E16, bias, top2);

    merge_compact_kernel<<<128, 256, 0, stream>>>(top2, in, k_final, list, count, zc);

    rescore_kernel<<<dim3(32, 16), 256, 0, stream>>>(zc, E, bias, count, rb);
    apply_kernel<<<8, 256, 0, stream>>>(list, count, rb, k_final);

    gather_kernel<<<N_PTS / 64, 256, 0, stream>>>(in, E, k_final, out, sumsq);
    finalize_kernel<<<1, 1, 0, stream>>>(sumsq, out + 16777216);
}

// Round 10
// 500.075 us; speedup vs baseline: 1.2819x; 1.2145x over previous
//
#include <hip/hip_runtime.h>

#define N_PTS 32768
#define DIM   512
#define KCODES 4096
#define HW    1024
#define MARGIN 0.125f
#define MAXFLAG 2048

typedef _Float16 half8 __attribute__((ext_vector_type(8)));
typedef float f32x4 __attribute__((ext_vector_type(4)));
typedef unsigned long long u64;

// ---- d_out scratch layout (bytes). gather overwrites everything at the end.
#define E16_OFF   0            // f16 [4096][512]    = 4 MB
#define BIAS_OFF  4194304      // f32 [4096]         = 16 KB
#define TOP2_OFF  4210688      // u64 [32768][2ks][2]= 1 MB   (ends 5259264)
#define ZC_OFF    5259264      // f32 [2048][512]    = 4 MB   (ends 9453568 < 64 MB)

// ---- ws layout: zeroed region first (memset only [0,16392))
// [0,16384)         rescore best u64[2048]
// [16384,16388)     count i32
// [16388,16392)     sumsq f32
// [16392,24584)     flag list i32[2048]
// [24584,155656)    k_final i32[32768]

__device__ __forceinline__ unsigned mono(float f) {
    unsigned u = __float_as_uint(f);
    return (u & 0x80000000u) ? ~u : (u | 0x80000000u);
}
__device__ __forceinline__ float unmono(unsigned m) {
    unsigned u = (m & 0x80000000u) ? (m & 0x7FFFFFFFu) : ~m;
    return __uint_as_float(u);
}

#define ASYNC16(src, dst) __builtin_amdgcn_global_load_lds( \
    (const __attribute__((address_space(1))) void*)(src), \
    (__attribute__((address_space(3))) void*)(dst), 16, 0, 0)

// ---------------------------------------------------------------- prep E (f16 convert + bias)
__global__ void prep_e_kernel(const float* __restrict__ E, _Float16* __restrict__ E16,
                              float* __restrict__ bias) {
    int k = blockIdx.x;
    int l = threadIdx.x; // 64
    const float4* row = (const float4*)(E + (size_t)k * DIM);
    float4 a = row[l * 2];
    float4 b = row[l * 2 + 1];
    half8 h;
    h[0] = (_Float16)a.x; h[1] = (_Float16)a.y; h[2] = (_Float16)a.z; h[3] = (_Float16)a.w;
    h[4] = (_Float16)b.x; h[5] = (_Float16)b.y; h[6] = (_Float16)b.z; h[7] = (_Float16)b.w;
    *(half8*)(E16 + (size_t)k * DIM + l * 8) = h;
    float s = a.x * a.x + a.y * a.y + a.z * a.z + a.w * a.w +
              b.x * b.x + b.y * b.y + b.z * b.z + b.w * b.w;
#pragma unroll
    for (int off = 32; off > 0; off >>= 1) s += __shfl_down(s, off, 64);
    if (l == 0) bias[k] = 0.5f * s;
}

// ---------------------------------------------------------------- z-register-resident, E double-buffered scorer
// EXACT R0 revert (proven 268 us, absmax 0). grid (2 ksplit, 256 pt-blocks) x 256 threads.
// Block: 128 pts x 2048 codes. Wave w owns 32 pts (2 tiles of 16), full D=512 in
// registers (zf[2][16] half8). Phase = 32 codes staged in LDS buf[f&1]; loads for
// f+1 issued right after the single barrier.
__global__ __launch_bounds__(256, 2) void score16_kernel(
    const float* __restrict__ in, const _Float16* __restrict__ E16,
    const float* __restrict__ bias, u64* __restrict__ top2)
{
    // slot s = kc*128 + ct*64 + lane; each slot = 8 halfs (16 B). 32 KB per buffer.
    __shared__ alignas(16) _Float16 stage[2][2048 * 8];

    const int t    = threadIdx.x;
    const int lane = t & 63;
    const int w    = t >> 6;     // 0..3
    const int lm   = lane & 15;
    const int lq   = lane >> 4;  // 0..3
    const int ks   = blockIdx.x; // 0..1
    const int pt0  = blockIdx.y * 128;

    // ---- preload z fragments for this wave's 32 points (fp32 NCHW -> f16, RTN)
    half8 zf[2][16];
#pragma unroll
    for (int pt = 0; pt < 2; pt++) {
        const int n = pt0 + 32 * w + 16 * pt + lm;
        const float* zb = in + (size_t)(n >> 10) * (DIM * HW) + (n & 1023);
#pragma unroll
        for (int kc = 0; kc < 16; kc++) {
            const int d0 = kc * 32 + lq * 8;
            half8 h;
#pragma unroll
            for (int j = 0; j < 8; j++) h[j] = (_Float16)zb[(size_t)(d0 + j) << 10];
            zf[pt][kc] = h;
        }
    }

    const u64 PKNEG = ((u64)0x007FFFFFu) << 32;  // pack(-inf)
    u64 b1[2], b2[2];
    float thr2[2];
#pragma unroll
    for (int p = 0; p < 2; p++) { b1[p] = PKNEG; b2[p] = PKNEG; thr2[p] = -INFINITY; }

    // prologue: stage phase 0 into buf 0
    {
        const int code0 = ks * 2048;
#pragma unroll
        for (int i = 0; i < 8; i++) {
            const int kc = 4 * w + (i >> 1);
            const int ct = i & 1;
            ASYNC16(E16 + (size_t)(code0 + ct * 16 + lm) * DIM + kc * 32 + lq * 8,
                    &stage[0][(size_t)(w * 512 + i * 64) << 3]);
        }
    }

    for (int f = 0; f < 64; f++) {
        const int code0 = ks * 2048 + f * 32;
        const int buf = f & 1;
        __syncthreads();   // drains vmcnt(0): buf[f&1] ready; gates reuse of buf[(f+1)&1]
        // ---- issue loads for phase f+1 (wraps harmlessly at f=63)
        {
            const int cn = ks * 2048 + ((f + 1) & 63) * 32;
#pragma unroll
            for (int i = 0; i < 8; i++) {
                const int kc = 4 * w + (i >> 1);
                const int ct = i & 1;
                ASYNC16(E16 + (size_t)(cn + ct * 16 + lm) * DIM + kc * 32 + lq * 8,
                        &stage[buf ^ 1][(size_t)(w * 512 + i * 64) << 3]);
            }
        }
        // ---- acc init with exact fp32 -bias
        f32x4 acc[2][2];
#pragma unroll
        for (int ct = 0; ct < 2; ct++) {
            const float4 bv = *(const float4*)&bias[code0 + ct * 16 + lq * 4];
            f32x4 bi; bi[0] = -bv.x; bi[1] = -bv.y; bi[2] = -bv.z; bi[3] = -bv.w;
            acc[ct][0] = bi; acc[ct][1] = bi;
        }
        // ---- 64 MFMAs from LDS A-frags x register z-frags
#pragma unroll
        for (int kc = 0; kc < 16; kc++) {
            half8 a0 = *(const half8*)&stage[buf][(size_t)(kc * 128 + lane) << 3];
            half8 a1 = *(const half8*)&stage[buf][(size_t)(kc * 128 + 64 + lane) << 3];
            acc[0][0] = __builtin_amdgcn_mfma_f32_16x16x32_f16(a0, zf[0][kc], acc[0][0], 0, 0, 0);
            acc[0][1] = __builtin_amdgcn_mfma_f32_16x16x32_f16(a0, zf[1][kc], acc[0][1], 0, 0, 0);
            acc[1][0] = __builtin_amdgcn_mfma_f32_16x16x32_f16(a1, zf[0][kc], acc[1][0], 0, 0, 0);
            acc[1][1] = __builtin_amdgcn_mfma_f32_16x16x32_f16(a1, zf[1][kc], acc[1][1], 0, 0, 0);
        }
        // ---- running top-2 insert (threshold fast path)
#pragma unroll
        for (int pt = 0; pt < 2; pt++) {
#pragma unroll
            for (int ct = 0; ct < 2; ct++) {
                f32x4 a = acc[ct][pt];
                bool hit = (a[0] > thr2[pt]) | (a[1] > thr2[pt]) |
                           (a[2] > thr2[pt]) | (a[3] > thr2[pt]);
                if (__any(hit)) {
#pragma unroll
                    for (int r = 0; r < 4; r++) {
                        float v = a[r];
                        if (v > thr2[pt]) {
                            int code = code0 + ct * 16 + lq * 4 + r;
                            u64 pk = ((u64)mono(v) << 32) | (unsigned)(0xFFFu ^ (unsigned)code);
                            if (pk > b1[pt]) { b2[pt] = b1[pt]; b1[pt] = pk; }
                            else if (pk > b2[pt]) { b2[pt] = pk; }
                            thr2[pt] = unmono((unsigned)(b2[pt] >> 32));
                        }
                    }
                }
            }
        }
    }
    // ---- merge across lq groups (lanes lm, lm+16, lm+32, lm+48 share a point)
#pragma unroll
    for (int pt = 0; pt < 2; pt++) {
#pragma unroll
        for (int m = 16; m <= 32; m <<= 1) {
            u64 o1 = __shfl_xor(b1[pt], m, 64);
            u64 o2 = __shfl_xor(b2[pt], m, 64);
            u64 m1 = b1[pt] > o1 ? b1[pt] : o1;
            u64 lo = b1[pt] > o1 ? o1 : b1[pt];
            u64 mm = b2[pt] > o2 ? b2[pt] : o2;
            b2[pt] = lo > mm ? lo : mm;
            b1[pt] = m1;
        }
    }
    if (lq == 0) {
#pragma unroll
        for (int pt = 0; pt < 2; pt++) {
            const size_t p = (size_t)(pt0 + 32 * w + 16 * pt + lm);
            top2[p * 4 + ks * 2]     = b1[pt];
            top2[p * 4 + ks * 2 + 1] = b2[pt];
        }
    }
}

// ---------------------------------------------------------------- merge 2 k-splits + flag (copy moved to zc_fill)
__global__ void merge_compact_kernel(const u64* __restrict__ top2,
                                     int* __restrict__ k_final, int* __restrict__ list,
                                     int* __restrict__ count) {
    int pt = blockIdx.x * 256 + threadIdx.x;
    const u64* p = top2 + (size_t)pt * 4;
    u64 B1 = 0, B2 = 0;
#pragma unroll
    for (int ks = 0; ks < 2; ks++) {
        u64 p1 = p[ks * 2], p2 = p[ks * 2 + 1];
        u64 m1 = B1 > p1 ? B1 : p1;
        u64 lo = B1 > p1 ? p1 : B1;
        u64 mm = B2 > p2 ? B2 : p2;
        B2 = lo > mm ? lo : mm;
        B1 = m1;
    }
    k_final[pt] = 0xFFF ^ (int)(B1 & 0xFFFull);
    float s1 = unmono((unsigned)(B1 >> 32));
    float s2 = unmono((unsigned)(B2 >> 32));
    if (s1 - s2 < MARGIN) {
        int idx = atomicAdd(count, 1);
        if (idx < MAXFLAG) list[idx] = pt;
    }
}

// ---------------------------------------------------------------- parallel zc fill: one wave per flagged point
// 64 lanes issue the 512 strided loads in parallel (8 per lane, independent),
// stores coalesced. Replaces merge_compact's serial per-thread 512-load copy.
__global__ __launch_bounds__(256) void zc_fill_kernel(const float* __restrict__ in,
                                                      const int* __restrict__ list,
                                                      const int* __restrict__ count,
                                                      float* __restrict__ zc) {
    int cnt = *count; if (cnt > MAXFLAG) cnt = MAXFLAG;
    const int wid  = blockIdx.x * 4 + (threadIdx.x >> 6);
    const int lane = threadIdx.x & 63;
    for (int i = wid; i < cnt; i += 256) {
        const int pt = list[i];
        const float* zb = in + (size_t)(pt >> 10) * (DIM * HW) + (pt & 1023);
        float* dst = zc + (size_t)i * DIM;
#pragma unroll
        for (int j = 0; j < 8; j++) {
            const int d = j * 64 + lane;
            dst[d] = zb[(size_t)d << 10];
        }
    }
}

// ---------------------------------------------------------------- exact fp32 rescore (coalesced zc reads)
__global__ __launch_bounds__(256) void rescore_kernel(
    const float* __restrict__ zc, const float* __restrict__ E,
    const float* __restrict__ bias, const int* __restrict__ count,
    u64* __restrict__ rb)
{
    __shared__ float As[16][128];
    __shared__ float Bs[16][132];

    int cnt = *count; if (cnt > MAXFLAG) cnt = MAXFLAG;
    const int t  = threadIdx.x;
    const int k0 = blockIdx.x * 128;
    const int r0 = blockIdx.y * 128;
    if (r0 >= cnt) return;

    float acc[8][8];
#pragma unroll
    for (int i = 0; i < 8; i++)
#pragma unroll
        for (int j = 0; j < 8; j++) acc[i][j] = 0.f;

    const int ra = (t >> 4) << 2;
    const int cb = (t & 15) << 2;

    for (int d0 = 0; d0 < DIM; d0 += 16) {
        {
            int j   = t >> 2;
            int dd4 = (t & 3) << 2;
            int rA = r0 + j;        if (rA >= cnt) rA = cnt - 1;
            int rB = r0 + j + 64;   if (rB >= cnt) rB = cnt - 1;
            float4 v0 = *(const float4*)&zc[(size_t)rA * DIM + d0 + dd4];
            float4 v1 = *(const float4*)&zc[(size_t)rB * DIM + d0 + dd4];
            As[dd4 + 0][j] = v0.x; As[dd4 + 1][j] = v0.y;
            As[dd4 + 2][j] = v0.z; As[dd4 + 3][j] = v0.w;
            As[dd4 + 0][j + 64] = v1.x; As[dd4 + 1][j + 64] = v1.y;
            As[dd4 + 2][j + 64] = v1.z; As[dd4 + 3][j + 64] = v1.w;
        }
        {
            int j   = t >> 2;
            int dd4 = (t & 3) << 2;
            const float* p = E + (size_t)(k0 + j) * DIM + d0 + dd4;
            float4 v0 = *(const float4*)p;
            float4 v1 = *(const float4*)(p + (size_t)64 * DIM);
            Bs[dd4 + 0][j] = v0.x; Bs[dd4 + 1][j] = v0.y;
            Bs[dd4 + 2][j] = v0.z; Bs[dd4 + 3][j] = v0.w;
            Bs[dd4 + 0][j + 64] = v1.x; Bs[dd4 + 1][j + 64] = v1.y;
            Bs[dd4 + 2][j + 64] = v1.z; Bs[dd4 + 3][j + 64] = v1.w;
        }
        __syncthreads();
#pragma unroll
        for (int dd = 0; dd < 16; dd++) {
            float4 a0 = *(const float4*)&As[dd][ra];
            float4 a1 = *(const float4*)&As[dd][ra + 64];
            float4 b0 = *(const float4*)&Bs[dd][cb];
            float4 b1v = *(const float4*)&Bs[dd][cb + 64];
            float av[8] = {a0.x, a0.y, a0.z, a0.w, a1.x, a1.y, a1.z, a1.w};
            float bv[8] = {b0.x, b0.y, b0.z, b0.w, b1v.x, b1v.y, b1v.z, b1v.w};
#pragma unroll
            for (int i = 0; i < 8; i++)
#pragma unroll
                for (int j = 0; j < 8; j++)
                    acc[i][j] = fmaf(av[i], bv[j], acc[i][j]);
        }
        __syncthreads();
    }

    float bcol[8];
#pragma unroll
    for (int j = 0; j < 8; j++) {
        int k = k0 + ((j < 4) ? (cb + j) : (64 + cb + j - 4));
        bcol[j] = bias[k];
    }
    u64 pk[8];
#pragma unroll
    for (int i = 0; i < 8; i++) {
        u64 bestp = 0ull;
#pragma unroll
        for (int j = 0; j < 8; j++) {
            int k = k0 + ((j < 4) ? (cb + j) : (64 + cb + j - 4));
            float s = acc[i][j] - bcol[j];
            u64 p = ((u64)mono(s) << 32) | (u64)(~(unsigned)k);
            if (p > bestp) bestp = p;
        }
        pk[i] = bestp;
    }
#pragma unroll
    for (int i = 0; i < 8; i++) {
#pragma unroll
        for (int off = 8; off > 0; off >>= 1) {
            u64 o = __shfl_down(pk[i], off, 16);
            if (o > pk[i]) pk[i] = o;
        }
    }
    if ((t & 15) == 0) {
#pragma unroll
        for (int i = 0; i < 8; i++) {
            int row = r0 + ((i < 4) ? (ra + i) : (64 + ra + i - 4));
            int slot = row < cnt ? row : cnt - 1;
            atomicMax(&rb[slot], pk[i]);
        }
    }
}

__global__ void apply_kernel(const int* __restrict__ list, const int* __restrict__ count,
                             const u64* __restrict__ rb, int* __restrict__ k_final) {
    int i = blockIdx.x * 256 + threadIdx.x;
    int cnt = *count; if (cnt > MAXFLAG) cnt = MAXFLAG;
    if (i < cnt) k_final[list[i]] = (int)(~(unsigned)(rb[i] & 0xffffffffull));
}

// ---------------------------------------------------------------- gather + loss
__global__ void gather_kernel(const float* __restrict__ in, const float* __restrict__ E,
                              const int* __restrict__ k_final,
                              float* __restrict__ out, float* __restrict__ sumsq)
{
    const int t  = threadIdx.x;
    const int tx = t & 63;
    const int ty = t >> 6;
    const int n  = blockIdx.x * 64 + tx;
    const int k  = k_final[n];
    const float* erow = E + (size_t)k * DIM;
    const size_t base = (size_t)(n >> 10) * (DIM * HW) + (n & 1023);
    float local = 0.f;
    for (int d = ty; d < DIM; d += 4) {
        float q = erow[d];
        size_t idx = base + ((size_t)d << 10);
        float z = in[idx];
        out[idx] = q;
        float df = z - q;
        local = fmaf(df, df, local);
    }
#pragma unroll
    for (int off = 32; off > 0; off >>= 1) local += __shfl_down(local, off, 64);
    __shared__ float red[4];
    if (tx == 0) red[ty] = local;
    __syncthreads();
    if (t == 0) atomicAdd(sumsq, red[0] + red[1] + red[2] + red[3]);
}

__global__ void finalize_kernel(const float* __restrict__ sumsq, float* __restrict__ out_loss) {
    *out_loss = 1.25f * (*sumsq) * (1.0f / 16777216.0f);
}

// ----------------------------------------------------------------
extern "C" void kernel_launch(void* const* d_in, const int* in_sizes, int n_in,
                              void* d_out, int out_size, void* d_ws, size_t ws_size,
                              hipStream_t stream) {
    const float* in = (const float*)d_in[0];
    const float* E  = (const float*)d_in[1];
    float* out = (float*)d_out;
    char* ob = (char*)d_out;

    _Float16* E16 = (_Float16*)(ob + E16_OFF);
    float* bias   = (float*)(ob + BIAS_OFF);
    u64* top2     = (u64*)(ob + TOP2_OFF);
    float* zc     = (float*)(ob + ZC_OFF);

    u64* rb      = (u64*)d_ws;
    int* count   = (int*)((char*)d_ws + 16384);
    float* sumsq = (float*)((char*)d_ws + 16388);
    int* list    = (int*)((char*)d_ws + 16392);
    int* k_final = (int*)((char*)d_ws + 24584);

    hipMemsetAsync(d_ws, 0, 16392, stream);

    prep_e_kernel<<<KCODES, 64, 0, stream>>>(E, E16, bias);

    score16_kernel<<<dim3(2, 256), 256, 0, stream>>>(in, E16, bias, top2);

    merge_compact_kernel<<<128, 256, 0, stream>>>(top2, k_final, list, count);
    zc_fill_kernel<<<64, 256, 0, stream>>>(in, list, count, zc);

    rescore_kernel<<<dim3(32, 16), 256, 0, stream>>>(zc, E, bias, count, rb);
    apply_kernel<<<8, 256, 0, stream>>>(list, count, rb, k_final);

    gather_kernel<<<N_PTS / 64, 256, 0, stream>>>(in, E, k_final, out, sumsq);
    finalize_kernel<<<1, 1, 0, stream>>>(sumsq, out + 16777216);
}